// Round 6
// baseline (834.703 us; speedup 1.0000x reference)
//
#include <hip/hip_runtime.h>
#include <cstdint>
#include <cstddef>

// ---------------------------------------------------------------------------
// VirtualNodeGNN: 3x GENConv(softmax aggr) + virtual node + mean pool.
// R19 = R18 resubmitted unchanged (R18's bench died on container acquisition,
// kernel never ran; audit found no hang/crash class: uniform barriers, LDS
// 71.75KB*2 <= 160KB, no buffer-reuse race).
// R18: fused MLP retry with the R14 failure fixed.
//   R14 fused at 64-row/120KB -> 1 block/CU -> every barrier drain on the
//   critical path -> 159us/layer. R18 fuses at 32-row/71.7KB -> 2 blocks/CU
//   (drains mutually hide across blocks; the 85->78 gemm2 gain in R17 came
//   from exactly this mechanism). Eliminates the t1 HBM round trip
//   (204 MB/layer) and one launch/layer. GEMM1 -> LDS t1 (swizzled) ->
//   in-LDS LN+ReLU -> GEMM2 from LDS; one 16KB B buffer streams W1 then W2.
//   Also: k_aggregate edge loop unrolled x2 (avg deg 2; pair the dependent
//   csr_src->hn gathers to halve exposed latency).
// ---------------------------------------------------------------------------

typedef _Float16 half8_t __attribute__((ext_vector_type(8)));
typedef _Float16 half4_t __attribute__((ext_vector_type(4)));
typedef float    floatx4 __attribute__((ext_vector_type(4)));

#define DEVINL __device__ __forceinline__

DEVINL float wave_sum(float v) {
#pragma unroll
  for (int m = 32; m; m >>= 1) v += __shfl_xor(v, m, 64);
  return v;
}

// ------------------------------- node encoder ------------------------------
__global__ __launch_bounds__(256) void k_node_enc(
    const float* __restrict__ x, const float* __restrict__ W,
    const float* __restrict__ bias, _Float16* __restrict__ h, int Nr) {
  __shared__ float sW[9 * 256];
  __shared__ float sb[256];
  __shared__ float sx[72];
  const int j = threadIdx.x;
#pragma unroll
  for (int k = 0; k < 9; ++k) sW[k * 256 + j] = W[k * 256 + j];
  sb[j] = bias[j];
  const int row0 = blockIdx.x * 8;
  if (j < 72) {
    int p = row0 * 9 + j;
    sx[j] = (p < Nr * 9) ? x[p] : 0.f;
  }
  __syncthreads();
  for (int r = 0; r < 8; ++r) {
    int row = row0 + r;
    if (row >= Nr) break;
    float acc = sb[j];
#pragma unroll
    for (int k = 0; k < 9; ++k) acc = fmaf(sx[r * 9 + k], sW[k * 256 + j], acc);
    h[(size_t)row * 256 + j] = (_Float16)acc;
  }
}

// ---------------- batch ptr via binary search (batch sorted) ---------------
__global__ void k_bptr(const int* __restrict__ batch, int* __restrict__ bptr,
                       int N_, int B_) {
  int b = blockIdx.x * 256 + threadIdx.x;
  if (b > B_) return;
  int lo = 0, hi = N_;
  while (lo < hi) {
    int mid = (lo + hi) >> 1;
    if (batch[mid] < b) lo = mid + 1; else hi = mid;
  }
  bptr[b] = lo;
}

// ------------------------- CSR build (dst-sorted) --------------------------
__global__ void k_deg(const int* __restrict__ ei, int* __restrict__ deg, int E_) {
  int e = blockIdx.x * 256 + threadIdx.x;
  if (e < E_) atomicAdd(&deg[ei[E_ + e]], 1);  // row 1 of edge_index = dst
}

__global__ __launch_bounds__(256) void k_scan1(
    const int* __restrict__ in, int* __restrict__ out1, int* __restrict__ bsum, int n) {
  __shared__ int tmp[256];
  const int t = threadIdx.x;
  const int base = blockIdx.x * 1024;
  int v[4];
  int run = 0;
#pragma unroll
  for (int i = 0; i < 4; ++i) {
    int p = base + t * 4 + i;
    int xv = (p < n) ? in[p] : 0;
    run += xv;
    v[i] = run;
  }
  tmp[t] = run;
  __syncthreads();
  for (int off = 1; off < 256; off <<= 1) {
    int u = (t >= off) ? tmp[t - off] : 0;
    __syncthreads();
    tmp[t] += u;
    __syncthreads();
  }
  int excl = tmp[t] - run;
#pragma unroll
  for (int i = 0; i < 4; ++i) {
    int p = base + t * 4 + i;
    if (p < n) out1[p] = v[i] + excl;
  }
  if (t == 255) bsum[blockIdx.x] = tmp[255];
}

__global__ void k_scan2(int* bsum, int nb, int* ptr0) {
  if (threadIdx.x == 0 && blockIdx.x == 0) {
    int run = 0;
    for (int i = 0; i < nb; ++i) { int xv = bsum[i]; bsum[i] = run; run += xv; }
    ptr0[0] = 0;
  }
}

__global__ __launch_bounds__(256) void k_scan3(int* out1, const int* __restrict__ bsum, int n) {
  int add = bsum[blockIdx.x];
  int p0 = blockIdx.x * 1024 + threadIdx.x * 4;
#pragma unroll
  for (int i = 0; i < 4; ++i) {
    int p = p0 + i;
    if (p < n) out1[p] += add;
  }
}

__global__ void k_copy(const int* __restrict__ a, int* __restrict__ b, int n) {
  int i = blockIdx.x * 256 + threadIdx.x;
  if (i < n) b[i] = a[i];
}

__global__ void k_csrfill(const int* __restrict__ ei, int* __restrict__ cursor,
                          int* __restrict__ csr_src, int* __restrict__ csr_eid, int E_) {
  int e = blockIdx.x * 256 + threadIdx.x;
  if (e < E_) {
    int d = ei[E_ + e];
    int pos = atomicAdd(&cursor[d], 1);
    csr_src[pos] = ei[e];
    csr_eid[pos] = e;
  }
}

__global__ void k_vninit(const float* __restrict__ emb, float* __restrict__ vn) {
  vn[(size_t)blockIdx.x * 256 + threadIdx.x] = emb[threadIdx.x];
}

// ----------------- all-weights transpose+convert (one launch) --------------
__global__ __launch_bounds__(256) void k_wcvt_all(
    const float* __restrict__ W1, const float* __restrict__ W2,
    _Float16* __restrict__ W1T, _Float16* __restrict__ W2T) {
  int idx = blockIdx.x * 256 + threadIdx.x;
  int mat = idx >> 17;
  int rem = idx & 131071;
  if (mat < 3) {
    int k = rem >> 9, n = rem & 511;
    W1T[(size_t)mat * 131072 + (size_t)n * 256 + k] =
        (_Float16)W1[(size_t)mat * 131072 + rem];
  } else {
    int m = mat - 3;
    int k = rem >> 8, n = rem & 255;
    W2T[(size_t)m * 131072 + (size_t)n * 512 + k] =
        (_Float16)W2[(size_t)m * 131072 + rem];
  }
}

// ------------------------------ LayerNorm 256 ------------------------------
// used once (layer 1, no vn pending)
__global__ __launch_bounds__(256) void k_ln256(
    const _Float16* __restrict__ h, const float* __restrict__ g,
    const float* __restrict__ b, _Float16* __restrict__ out, int Nr) {
  int row = blockIdx.x * 4 + (threadIdx.x >> 6);
  if (row >= Nr) return;
  int lane = threadIdx.x & 63;
  half4_t xh = *(const half4_t*)(h + (size_t)row * 256 + lane * 4);
  float x0 = (float)xh[0], x1 = (float)xh[1], x2 = (float)xh[2], x3 = (float)xh[3];
  float s = wave_sum(x0 + x1 + x2 + x3);
  float mu = s * (1.f / 256.f);
  float d0 = x0 - mu, d1 = x1 - mu, d2 = x2 - mu, d3 = x3 - mu;
  float v = wave_sum(d0 * d0 + d1 * d1 + d2 * d2 + d3 * d3);
  float rstd = rsqrtf(v * (1.f / 256.f) + 1e-5f);
  float4 gv = *(const float4*)(g + lane * 4);
  float4 bv = *(const float4*)(b + lane * 4);
  half4_t o;
  o[0] = (_Float16)fmaxf(d0 * rstd * gv.x + bv.x, 0.f);
  o[1] = (_Float16)fmaxf(d1 * rstd * gv.y + bv.y, 0.f);
  o[2] = (_Float16)fmaxf(d2 * rstd * gv.z + bv.z, 0.f);
  o[3] = (_Float16)fmaxf(d3 * rstd * gv.w + bv.w, 0.f);
  *(half4_t*)(out + (size_t)row * 256 + lane * 4) = o;
}

// --------------------------- softmax aggregation ---------------------------
// One node per wave; edge loop unrolled x2 with both gathers issued before
// use (avg deg = 2: the dependent csr_src->hn chain is the whole kernel).
__global__ __launch_bounds__(256) void k_aggregate(
    const _Float16* __restrict__ hn, const float* __restrict__ eattr,
    const float* __restrict__ edgeW, const float* __restrict__ edgeB,
    const int* __restrict__ indptr, const int* __restrict__ csr_src,
    const int* __restrict__ csr_eid, const float* __restrict__ tptr,
    _Float16* __restrict__ agg, int Nr) {
  int node = blockIdx.x * 4 + (threadIdx.x >> 6);
  if (node >= Nr) return;
  int lane = threadIdx.x & 63;
  int j0 = lane * 4;
  float4 w0 = *(const float4*)(edgeW + j0);
  float4 w1 = *(const float4*)(edgeW + 256 + j0);
  float4 w2 = *(const float4*)(edgeW + 512 + j0);
  float4 wb = *(const float4*)(edgeB + j0);
  float W0[4] = {w0.x, w0.y, w0.z, w0.w};
  float W1r[4] = {w1.x, w1.y, w1.z, w1.w};
  float W2r[4] = {w2.x, w2.y, w2.z, w2.w};
  float WB[4] = {wb.x, wb.y, wb.z, wb.w};
  float tval = tptr[0];
  int e0 = indptr[node], e1 = indptr[node + 1];
  float D[4] = {0.f, 0.f, 0.f, 0.f};
  float Nu[4] = {0.f, 0.f, 0.f, 0.f};
  int s = e0;
  for (; s + 2 <= e1; s += 2) {
    int sa = csr_src[s], sb = csr_src[s + 1];
    int ea = csr_eid[s], eb = csr_eid[s + 1];
    float ax0 = eattr[(size_t)ea * 3 + 0];
    float ax1 = eattr[(size_t)ea * 3 + 1];
    float ax2 = eattr[(size_t)ea * 3 + 2];
    float bx0 = eattr[(size_t)eb * 3 + 0];
    float bx1 = eattr[(size_t)eb * 3 + 1];
    float bx2 = eattr[(size_t)eb * 3 + 2];
    half4_t ha = *(const half4_t*)(hn + (size_t)sa * 256 + j0);
    half4_t hb = *(const half4_t*)(hn + (size_t)sb * 256 + j0);
#pragma unroll
    for (int i = 0; i < 4; ++i) {
      float ea_j = fmaf(ax0, W0[i], fmaf(ax1, W1r[i], fmaf(ax2, W2r[i], WB[i])));
      float ma = fmaxf((float)ha[i] + ea_j, 0.f) + 1e-7f;
      float pa = __expf(ma * tval);
      D[i] += pa;
      Nu[i] = fmaf(pa, ma, Nu[i]);
      float eb_j = fmaf(bx0, W0[i], fmaf(bx1, W1r[i], fmaf(bx2, W2r[i], WB[i])));
      float mb = fmaxf((float)hb[i] + eb_j, 0.f) + 1e-7f;
      float pb = __expf(mb * tval);
      D[i] += pb;
      Nu[i] = fmaf(pb, mb, Nu[i]);
    }
  }
  if (s < e1) {
    int sa = csr_src[s];
    int ea = csr_eid[s];
    float ax0 = eattr[(size_t)ea * 3 + 0];
    float ax1 = eattr[(size_t)ea * 3 + 1];
    float ax2 = eattr[(size_t)ea * 3 + 2];
    half4_t ha = *(const half4_t*)(hn + (size_t)sa * 256 + j0);
#pragma unroll
    for (int i = 0; i < 4; ++i) {
      float ea_j = fmaf(ax0, W0[i], fmaf(ax1, W1r[i], fmaf(ax2, W2r[i], WB[i])));
      float ma = fmaxf((float)ha[i] + ea_j, 0.f) + 1e-7f;
      float pa = __expf(ma * tval);
      D[i] += pa;
      Nu[i] = fmaf(pa, ma, Nu[i]);
    }
  }
  half4_t hs = *(const half4_t*)(hn + (size_t)node * 256 + j0);
  half4_t res;
#pragma unroll
  for (int i = 0; i < 4; ++i)
    res[i] = (_Float16)(Nu[i] / (D[i] + 1e-16f) + (float)hs[i]);
  *(half4_t*)(agg + (size_t)node * 256 + j0) = res;
}

// --------------------------- fused MLP (per layer) -------------------------
// h[32-row tile] += (LN_relu(agg @ W1 + b1) @ W2 + b2) (+ vn[batch]).
// Block = 32 rows, 256 threads (4 waves). LDS 71.7KB -> 2 blocks/CU (the
// R14 fix: drains of the two resident blocks mutually hide).
//   GEMM1: A (32x256) staged once XOR-swizzled; W1T k-tiles (128n x 64k,
//     16KB) stream through ldsB with depth-1 reg prefetch; per-n-tile
//     epilogue adds b1, accumulates row stats, spills f16 into swizzled
//     ldsT1 (32x512 = 32KB).
//   LN+ReLU in place on ldsT1 (stats combined via sred/sac).
//   GEMM2: A-frags from ldsT1; W2T k-tiles stream through the same ldsB.
//   Epilogue: per-wave stride-68 staging in (dead) ldsA, coalesced h RMW.
template <int VN>
__global__ __launch_bounds__(256, 2) void k_fmlp(
    const _Float16* __restrict__ A, const _Float16* __restrict__ B1T,
    const float* __restrict__ b1, const float* __restrict__ lg,
    const float* __restrict__ lb, const _Float16* __restrict__ B2T,
    const float* __restrict__ b2, const float* __restrict__ vn,
    const int* __restrict__ batch, _Float16* __restrict__ outf, int M) {
  __shared__ _Float16 ldsT1[32 * 512];   // 32 KB: t1 tile (swizzled)
  __shared__ _Float16 ldsA[32 * 256];    // 16 KB: A stage -> epilogue stage
  __shared__ _Float16 ldsB[1024 * 8];    // 16 KB: B1/B2 k-tile (128n x 64k)
  __shared__ float sb1[512];
  __shared__ float sg[512];
  __shared__ float sbt[512];
  __shared__ float sb2[256];
  __shared__ float sred[32 * 4];         // [row][half*2 + {sum,sum2}]
  __shared__ float2 sac[32];             // per-row (rs, -mu*rs)

  const int tid = threadIdx.x;
  const int lane = tid & 63;
  const int wv = tid >> 6;               // 0..3
  const int wband = wv >> 1;             // row band (16 rows)
  const int whalf = wv & 1;              // col half within 128-n-tile
  const int q = lane >> 4;
  const int l16 = lane & 15;
  const int m0 = blockIdx.x * 32;

  // ---- params to LDS ----
  sb1[tid] = b1[tid]; sb1[tid + 256] = b1[tid + 256];
  sg[tid]  = lg[tid]; sg[tid + 256]  = lg[tid + 256];
  sbt[tid] = lb[tid]; sbt[tid + 256] = lb[tid + 256];
  sb2[tid] = b2[tid];

  // ---- stage A once: 1024 16B chunks; slot (r,s) holds chunk s^(r&7) ----
  {
    half8_t tmp[4];
    int ss[4];
#pragma unroll
    for (int g = 0; g < 4; ++g) {
      int s = g * 256 + tid;             // 0..1023
      int r = s >> 5;                    // 0..31
      int c = (s & 31) ^ (r & 7);        // XOR touches low 3 bits only
      int rowA = m0 + r;
      rowA = rowA < M ? rowA : (M - 1);
      tmp[g] = *(const half8_t*)(A + (size_t)rowA * 256 + c * 8);
      ss[g] = s;
    }
#pragma unroll
    for (int g = 0; g < 4; ++g)
      *(half8_t*)(ldsA + (size_t)ss[g] * 8) = tmp[g];
  }

  // ---- B staging offsets (tile = 128 n-rows x 64 k) ----
  size_t offB1[4], offB2[4];
  int ldsOffB[4];
#pragma unroll
  for (int i = 0; i < 4; ++i) {
    int p = (i * 4 + wv) * 64 + lane;    // 0..1023
    int r = p >> 3;
    int s = p & 7;
    int gg = s ^ (r & 7);
    offB1[i] = (size_t)r * 256 + gg * 8; // W1T row stride 256
    offB2[i] = (size_t)r * 512 + gg * 8; // W2T row stride 512
    ldsOffB[i] = p * 8;
  }
  half8_t rb[4];
  auto loadB1 = [&](int j) {             // j = nt*4 + kt
    int nt = j >> 2, kt = j & 3;
    size_t base = (size_t)nt * 128 * 256 + (size_t)kt * 64;
#pragma unroll
    for (int i = 0; i < 4; ++i)
      rb[i] = *(const half8_t*)(B1T + base + offB1[i]);
  };
  auto loadB2 = [&](int j) {             // j = n2*8 + kt
    int n2 = j >> 3, kt = j & 7;
    size_t base = (size_t)n2 * 128 * 512 + (size_t)kt * 64;
#pragma unroll
    for (int i = 0; i < 4; ++i)
      rb[i] = *(const half8_t*)(B2T + base + offB2[i]);
  };
  auto writeB = [&]() {
#pragma unroll
    for (int i = 0; i < 4; ++i)
      *(half8_t*)(ldsB + ldsOffB[i]) = rb[i];
  };

  // ------------------------------ phase 1: GEMM1 ---------------------------
  floatx4 acc[4] = {};
  float sA[4] = {0.f, 0.f, 0.f, 0.f}, s2A[4] = {0.f, 0.f, 0.f, 0.f};

  loadB1(0);
  writeB();
  for (int j = 0; j < 16; ++j) {
    __syncthreads();                     // B tile j (A/params on j=0) visible
    if (j + 1 < 16) loadB1(j + 1);
    const int t = j & 3;
#pragma unroll
    for (int kk = 0; kk < 2; ++kk) {
      const int c8 = kk * 4 + q;         // k-chunk within 64-k tile
      const int cg = t * 8 + c8;         // global A k-chunk (0..31)
      int r = wband * 16 + l16;
      half8_t af = *(const half8_t*)(ldsA + (size_t)(r * 32 + (cg ^ (r & 7))) * 8);
      half8_t bf[4];
#pragma unroll
      for (int ct = 0; ct < 4; ++ct) {
        int n = whalf * 64 + ct * 16 + l16;
        bf[ct] = *(const half8_t*)(ldsB + (size_t)(n * 8 + (c8 ^ (n & 7))) * 8);
      }
#pragma unroll
      for (int ct = 0; ct < 4; ++ct)
        acc[ct] = __builtin_amdgcn_mfma_f32_16x16x32_f16(af, bf[ct], acc[ct], 0, 0, 0);
    }
    __syncthreads();                     // reads of tile j done
    if (j + 1 < 16) writeB();
    if ((j & 3) == 3) {                  // n-tile complete: spill into ldsT1
      int nt = j >> 2;
#pragma unroll
      for (int rr = 0; rr < 4; ++rr) {
        int rloc = wband * 16 + q * 4 + rr;
        float s = 0.f, s2 = 0.f;
#pragma unroll
        for (int ct = 0; ct < 4; ++ct) {
          int col = nt * 128 + whalf * 64 + ct * 16 + l16;
          float v = acc[ct][rr] + sb1[col];
          s += v;
          s2 += v * v;
          int cch = col >> 3;
          int slot = (cch & 56) | ((cch & 7) ^ (rloc & 7));
          ldsT1[(size_t)rloc * 512 + slot * 8 + (col & 7)] = (_Float16)v;
        }
        sA[rr] += s;
        s2A[rr] += s2;
      }
#pragma unroll
      for (int ct = 0; ct < 4; ++ct) acc[ct] = floatx4{0.f, 0.f, 0.f, 0.f};
    }
  }

  // ---- row stats: 16-lane reduce, per (row, col-half) into sred ----
#pragma unroll
  for (int rr = 0; rr < 4; ++rr) {
    float s = sA[rr], s2 = s2A[rr];
#pragma unroll
    for (int m = 1; m < 16; m <<= 1) {
      s += __shfl_xor(s, m, 64);
      s2 += __shfl_xor(s2, m, 64);
    }
    if (l16 == 0) {
      int rloc = wband * 16 + q * 4 + rr;
      sred[rloc * 4 + whalf * 2 + 0] = s;
      sred[rloc * 4 + whalf * 2 + 1] = s2;
    }
  }
  loadB2(0);                             // hide W2T latency under LN
  __syncthreads();                       // sred + all ldsT1 writes visible
  if (tid < 32) {
    float fs = sred[tid * 4 + 0] + sred[tid * 4 + 2];
    float fs2 = sred[tid * 4 + 1] + sred[tid * 4 + 3];
    float mu = fs * (1.f / 512.f);
    float var = fs2 * (1.f / 512.f) - mu * mu;
    float rs = rsqrtf(var + 1e-5f);
    sac[tid] = make_float2(rs, -mu * rs);
  }
  __syncthreads();

  // ---- LN + ReLU in place (thread = 1/8 of a row) ----
  {
    int r = tid >> 3;
    int t7 = tid & 7;
    float2 ac = sac[r];
#pragma unroll
    for (int g = 0; g < 8; ++g) {
      int slot = g * 8 + t7;
      int cch = (slot & 56) | ((slot & 7) ^ (r & 7));  // swizzle involutive
      half8_t v = *(half8_t*)(ldsT1 + (size_t)r * 512 + slot * 8);
      half8_t o;
      int c0 = cch * 8;
#pragma unroll
      for (int jj = 0; jj < 8; ++jj) {
        float e = fmaf((float)v[jj], ac.x, ac.y);
        o[jj] = (_Float16)fmaxf(fmaf(e, sg[c0 + jj], sbt[c0 + jj]), 0.f);
      }
      *(half8_t*)(ldsT1 + (size_t)r * 512 + slot * 8) = o;
    }
  }
  writeB();                              // B2 tile 0 (ldsB reads long done)

  // ------------------------------ phase 2: GEMM2 ---------------------------
  for (int n2 = 0; n2 < 2; ++n2) {
#pragma unroll 1
    for (int kt = 0; kt < 8; ++kt) {
      __syncthreads();                   // B2 tile (LN'd T1 first time) visible
      int j2 = n2 * 8 + kt;
      if (j2 + 1 < 16) loadB2(j2 + 1);
#pragma unroll
      for (int kk = 0; kk < 2; ++kk) {
        const int c8 = kk * 4 + q;
        const int ck = kt * 8 + c8;      // global k-chunk (0..63)
        int r = wband * 16 + l16;
        int slot = (ck & 56) | ((ck & 7) ^ (r & 7));
        half8_t af = *(const half8_t*)(ldsT1 + (size_t)(r * 64 + slot) * 8);
        half8_t bf[4];
#pragma unroll
        for (int ct = 0; ct < 4; ++ct) {
          int n = whalf * 64 + ct * 16 + l16;
          bf[ct] = *(const half8_t*)(ldsB + (size_t)(n * 8 + (c8 ^ (n & 7))) * 8);
        }
#pragma unroll
        for (int ct = 0; ct < 4; ++ct)
          acc[ct] = __builtin_amdgcn_mfma_f32_16x16x32_f16(af, bf[ct], acc[ct], 0, 0, 0);
      }
      __syncthreads();                   // reads of this B2 tile done
      if (j2 + 1 < 16) writeB();
    }
    // ---- epilogue n2: per-wave staging in dead ldsA, coalesced h RMW ----
    _Float16* epi = ldsA + (size_t)wv * (16 * 68);
#pragma unroll
    for (int rr = 0; rr < 4; ++rr) {
      int lr = q * 4 + rr;
      int row = m0 + wband * 16 + lr;
      int rowc = row < M ? row : (M - 1);
      int bb = 0;
      if constexpr (VN) bb = batch[rowc];
#pragma unroll
      for (int ct = 0; ct < 4; ++ct) {
        int cloc = ct * 16 + l16;
        int col = n2 * 128 + whalf * 64 + cloc;
        float v = acc[ct][rr] + sb2[col];
        if constexpr (VN) v += vn[(size_t)bb * 256 + col];
        epi[lr * 68 + cloc] = (_Float16)v;
      }
    }
#pragma unroll
    for (int it = 0; it < 2; ++it) {
      int lr = it * 8 + (lane >> 3);
      int row = m0 + wband * 16 + lr;
      if (row < M) {
        int c0 = (lane & 7) * 8;
        size_t gidx = (size_t)row * 256 + n2 * 128 + whalf * 64 + c0;
        half8_t hv = *(const half8_t*)(outf + gidx);
        half8_t ev = *(const half8_t*)(epi + lr * 68 + c0);
        half8_t o;
#pragma unroll
        for (int jj = 0; jj < 8; ++jj) o[jj] = (_Float16)((float)hv[jj] + (float)ev[jj]);
        *(half8_t*)(outf + gidx) = o;
      }
    }
#pragma unroll
    for (int ct = 0; ct < 4; ++ct) acc[ct] = floatx4{0.f, 0.f, 0.f, 0.f};
  }
}

// ------------- fused virtual-node update + next-layer LN -------------------
__global__ __launch_bounds__(256) void k_vnln(
    const _Float16* __restrict__ h, float* __restrict__ vn,
    const int* __restrict__ bptr, const float* __restrict__ g,
    const float* __restrict__ b, _Float16* __restrict__ hn) {
  __shared__ float red[3][256];
  __shared__ float svn[256];
  int bb = blockIdx.x;
  int w = threadIdx.x >> 6;
  int lane = threadIdx.x & 63;
  int n0 = bptr[bb], n1 = bptr[bb + 1];
  float a0 = 0.f, a1 = 0.f, a2 = 0.f, a3 = 0.f;
  for (int row = n0 + w; row < n1; row += 4) {
    half4_t xh = *(const half4_t*)(h + (size_t)row * 256 + lane * 4);
    a0 += (float)xh[0]; a1 += (float)xh[1];
    a2 += (float)xh[2]; a3 += (float)xh[3];
  }
  if (w > 0) {
    red[w - 1][lane * 4 + 0] = a0;
    red[w - 1][lane * 4 + 1] = a1;
    red[w - 1][lane * 4 + 2] = a2;
    red[w - 1][lane * 4 + 3] = a3;
  }
  __syncthreads();
  if (w == 0) {
    int c = n1 - n0;
    float ic = 1.f / (float)(c > 1 ? c : 1);
#pragma unroll
    for (int k = 0; k < 3; ++k) {
      a0 += red[k][lane * 4 + 0];
      a1 += red[k][lane * 4 + 1];
      a2 += red[k][lane * 4 + 2];
      a3 += red[k][lane * 4 + 3];
    }
    float4 vo = *(const float4*)(vn + (size_t)bb * 256 + lane * 4);
    vo.x += a0 * ic; vo.y += a1 * ic; vo.z += a2 * ic; vo.w += a3 * ic;
    *(float4*)(vn + (size_t)bb * 256 + lane * 4) = vo;
    svn[lane * 4 + 0] = vo.x;
    svn[lane * 4 + 1] = vo.y;
    svn[lane * 4 + 2] = vo.z;
    svn[lane * 4 + 3] = vo.w;
  }
  __syncthreads();
  float4 vv = *(const float4*)(svn + lane * 4);
  float4 gv = *(const float4*)(g + lane * 4);
  float4 bv = *(const float4*)(b + lane * 4);
  for (int row = n0 + w; row < n1; row += 4) {
    half4_t xh = *(const half4_t*)(h + (size_t)row * 256 + lane * 4);
    float x0 = (float)xh[0] + vv.x, x1 = (float)xh[1] + vv.y;
    float x2 = (float)xh[2] + vv.z, x3 = (float)xh[3] + vv.w;
    float s = wave_sum(x0 + x1 + x2 + x3);
    float mu = s * (1.f / 256.f);
    float d0 = x0 - mu, d1 = x1 - mu, d2 = x2 - mu, d3 = x3 - mu;
    float v = wave_sum(d0 * d0 + d1 * d1 + d2 * d2 + d3 * d3);
    float rstd = rsqrtf(v * (1.f / 256.f) + 1e-5f);
    half4_t o;
    o[0] = (_Float16)fmaxf(d0 * rstd * gv.x + bv.x, 0.f);
    o[1] = (_Float16)fmaxf(d1 * rstd * gv.y + bv.y, 0.f);
    o[2] = (_Float16)fmaxf(d2 * rstd * gv.z + bv.z, 0.f);
    o[3] = (_Float16)fmaxf(d3 * rstd * gv.w + bv.w, 0.f);
    *(half4_t*)(hn + (size_t)row * 256 + lane * 4) = o;
  }
}

// ---------- fused final vn update + LayerNorm + mean pool ------------------
__global__ __launch_bounds__(256) void k_vnlnpool(
    const _Float16* __restrict__ h, const float* __restrict__ vn,
    const int* __restrict__ bptr, const float* __restrict__ g,
    const float* __restrict__ b, float* __restrict__ out) {
  __shared__ float red[3][256];
  __shared__ float svn[256];
  int bb = blockIdx.x;
  int w = threadIdx.x >> 6;
  int lane = threadIdx.x & 63;
  int n0 = bptr[bb], n1 = bptr[bb + 1];
  int c = n1 - n0;
  float ic = 1.f / (float)(c > 1 ? c : 1);
  float a0 = 0.f, a1 = 0.f, a2 = 0.f, a3 = 0.f;
  for (int row = n0 + w; row < n1; row += 4) {
    half4_t xh = *(const half4_t*)(h + (size_t)row * 256 + lane * 4);
    a0 += (float)xh[0]; a1 += (float)xh[1];
    a2 += (float)xh[2]; a3 += (float)xh[3];
  }
  if (w > 0) {
    red[w - 1][lane * 4 + 0] = a0;
    red[w - 1][lane * 4 + 1] = a1;
    red[w - 1][lane * 4 + 2] = a2;
    red[w - 1][lane * 4 + 3] = a3;
  }
  __syncthreads();
  if (w == 0) {
#pragma unroll
    for (int k = 0; k < 3; ++k) {
      a0 += red[k][lane * 4 + 0];
      a1 += red[k][lane * 4 + 1];
      a2 += red[k][lane * 4 + 2];
      a3 += red[k][lane * 4 + 3];
    }
    float4 vo = *(const float4*)(vn + (size_t)bb * 256 + lane * 4);
    svn[lane * 4 + 0] = vo.x + a0 * ic;
    svn[lane * 4 + 1] = vo.y + a1 * ic;
    svn[lane * 4 + 2] = vo.z + a2 * ic;
    svn[lane * 4 + 3] = vo.w + a3 * ic;
  }
  __syncthreads();
  float4 vv = *(const float4*)(svn + lane * 4);
  float4 gv = *(const float4*)(g + lane * 4);
  float4 bv = *(const float4*)(b + lane * 4);
  a0 = a1 = a2 = a3 = 0.f;
  for (int row = n0 + w; row < n1; row += 4) {
    half4_t xh = *(const half4_t*)(h + (size_t)row * 256 + lane * 4);
    float x0 = (float)xh[0] + vv.x, x1 = (float)xh[1] + vv.y;
    float x2 = (float)xh[2] + vv.z, x3 = (float)xh[3] + vv.w;
    float s = wave_sum(x0 + x1 + x2 + x3);
    float mu = s * (1.f / 256.f);
    float d0 = x0 - mu, d1 = x1 - mu, d2 = x2 - mu, d3 = x3 - mu;
    float v = wave_sum(d0 * d0 + d1 * d1 + d2 * d2 + d3 * d3);
    float rstd = rsqrtf(v * (1.f / 256.f) + 1e-5f);
    a0 += fmaxf(d0 * rstd * gv.x + bv.x, 0.f);
    a1 += fmaxf(d1 * rstd * gv.y + bv.y, 0.f);
    a2 += fmaxf(d2 * rstd * gv.z + bv.z, 0.f);
    a3 += fmaxf(d3 * rstd * gv.w + bv.w, 0.f);
  }
  __syncthreads();  // red reuse
  if (w > 0) {
    red[w - 1][lane * 4 + 0] = a0;
    red[w - 1][lane * 4 + 1] = a1;
    red[w - 1][lane * 4 + 2] = a2;
    red[w - 1][lane * 4 + 3] = a3;
  }
  __syncthreads();
  if (w == 0) {
#pragma unroll
    for (int k = 0; k < 3; ++k) {
      a0 += red[k][lane * 4 + 0];
      a1 += red[k][lane * 4 + 1];
      a2 += red[k][lane * 4 + 2];
      a3 += red[k][lane * 4 + 3];
    }
    float4 o = {a0 * ic, a1 * ic, a2 * ic, a3 * ic};
    *(float4*)(out + (size_t)bb * 256 + lane * 4) = o;
  }
}

// ---------------------------------------------------------------------------
extern "C" void kernel_launch(void* const* d_in, const int* in_sizes, int n_in,
                              void* d_out, int out_size, void* d_ws, size_t ws_size,
                              hipStream_t stream) {
  const float* x      = (const float*)d_in[0];
  const int*   ei     = (const int*)d_in[1];
  const float* eattr  = (const float*)d_in[2];
  const int*   batch  = (const int*)d_in[3];
  const float* nodeW  = (const float*)d_in[4];
  const float* nodeB  = (const float*)d_in[5];
  const float* edgeW  = (const float*)d_in[6];
  const float* edgeB  = (const float*)d_in[7];
  const float* vnemb  = (const float*)d_in[8];
  const float* lng    = (const float*)d_in[9];
  const float* lnb    = (const float*)d_in[10];
  const float* tparam = (const float*)d_in[11];
  const float* W1     = (const float*)d_in[12];
  const float* b1     = (const float*)d_in[13];
  const float* mlng   = (const float*)d_in[14];
  const float* mlnb   = (const float*)d_in[15];
  const float* W2     = (const float*)d_in[16];
  const float* b2     = (const float*)d_in[17];
  float* out = (float*)d_out;

  const int N = in_sizes[3];         // 100000
  const int E = in_sizes[1] / 2;     // 200000
  const int B = out_size / 256;      // 2048

  char* p = (char*)d_ws;
  auto take = [&](size_t bytes) -> char* {
    char* r = p;
    p += (bytes + 255) & ~(size_t)255;
    return r;
  };
  _Float16*  h   = (_Float16*)take((size_t)N * 256 * 2);  // f16 residual stream
  _Float16*  hn  = (_Float16*)take((size_t)N * 256 * 2);  // pre-LN'd conv input
  _Float16*  agg = (_Float16*)take((size_t)N * 256 * 2);
  _Float16*  W1T = (_Float16*)take((size_t)3 * 512 * 256 * 2);
  _Float16*  W2T = (_Float16*)take((size_t)3 * 256 * 512 * 2);
  float*     vn  = (float*)take((size_t)B * 256 * 4);
  int*       bptr   = (int*)take((size_t)(B + 1) * 4);
  int*       deg    = (int*)take((size_t)N * 4);
  int*       indptr = (int*)take((size_t)(N + 1) * 4);
  int*       cursor = (int*)take((size_t)N * 4);
  int*       csr_src = (int*)take((size_t)E * 4);
  int*       csr_eid = (int*)take((size_t)E * 4);
  int*       bsum    = (int*)take(512 * 4);
  (void)ws_size; (void)n_in;

  hipMemsetAsync(deg, 0, (size_t)N * 4, stream);

  k_node_enc<<<(N + 7) / 8, 256, 0, stream>>>(x, nodeW, nodeB, h, N);
  k_bptr<<<(B + 256) / 256, 256, 0, stream>>>(batch, bptr, N, B);

  const int nbN = (N + 1023) / 1024;
  k_deg<<<(E + 255) / 256, 256, 0, stream>>>(ei, deg, E);
  k_scan1<<<nbN, 256, 0, stream>>>(deg, indptr + 1, bsum, N);
  k_scan2<<<1, 64, 0, stream>>>(bsum, nbN, indptr);
  k_scan3<<<nbN, 256, 0, stream>>>(indptr + 1, bsum, N);
  k_copy<<<(N + 255) / 256, 256, 0, stream>>>(indptr, cursor, N);
  k_csrfill<<<(E + 255) / 256, 256, 0, stream>>>(ei, cursor, csr_src, csr_eid, E);

  k_wcvt_all<<<3072, 256, 0, stream>>>(W1, W2, W1T, W2T);
  k_vninit<<<B, 256, 0, stream>>>(vnemb, vn);

  const int lnGrid = (N + 3) / 4;
  const int mTiles = (N + 31) / 32;

  // layer 1 pre-LN (no pending vn)
  k_ln256<<<lnGrid, 256, 0, stream>>>(h, lng + 256, lnb + 256, hn, N);
  for (int l = 1; l <= 3; ++l) {
    k_aggregate<<<lnGrid, 256, 0, stream>>>(hn, eattr, edgeW, edgeB, indptr, csr_src, csr_eid,
                                            tparam + (l - 1), agg, N);
    if (l == 1)
      k_fmlp<0><<<mTiles, 256, 0, stream>>>(
          agg, W1T + (size_t)(l - 1) * 512 * 256, b1 + (size_t)(l - 1) * 512,
          mlng + (size_t)(l - 1) * 512, mlnb + (size_t)(l - 1) * 512,
          W2T + (size_t)(l - 1) * 256 * 512, b2 + (size_t)(l - 1) * 256,
          nullptr, nullptr, h, N);
    else
      k_fmlp<1><<<mTiles, 256, 0, stream>>>(
          agg, W1T + (size_t)(l - 1) * 512 * 256, b1 + (size_t)(l - 1) * 512,
          mlng + (size_t)(l - 1) * 512, mlnb + (size_t)(l - 1) * 512,
          W2T + (size_t)(l - 1) * 256 * 512, b2 + (size_t)(l - 1) * 256,
          vn, batch, h, N);
    if (l < 3)  // fused: vn update + layer-(l+1) LN
      k_vnln<<<B, 256, 0, stream>>>(h, vn, bptr,
                                    lng + (size_t)(l + 1) * 256, lnb + (size_t)(l + 1) * 256, hn);
    else        // fused: vn update + final LN + mean pool
      k_vnlnpool<<<B, 256, 0, stream>>>(h, vn, bptr, lng, lnb, out);
  }
}